// Round 1
// baseline (113.795 us; speedup 1.0000x reference)
//
#include <hip/hip_runtime.h>
#include <math.h>

constexpr int D  = 1280;   // input dim
constexpr int H  = 64;     // hidden
constexpr int BM = 64;     // rows per block
constexpr int KC = 32;     // K chunk
constexpr int XS_STRIDE = KC + 4;  // 36 floats -> 144B rows (16B aligned, bank-safe)
constexpr int HS_STRIDE = H + 1;   // 65

// ---------------- quantum gates: 4-qubit statevector, bit weight BW = 8>>wire ----
template<int BW>
__device__ __forceinline__ void ry_gate(float re[16], float im[16], float theta) {
    float sn, cs;
    sincosf(0.5f * theta, &sn, &cs);
#pragma unroll
    for (int s0 = 0; s0 < 16; ++s0) {
        if (s0 & BW) continue;
        const int s1 = s0 | BW;
        float r0 = re[s0], i0 = im[s0], r1 = re[s1], i1 = im[s1];
        re[s0] = cs * r0 - sn * r1;  im[s0] = cs * i0 - sn * i1;
        re[s1] = sn * r0 + cs * r1;  im[s1] = sn * i0 + cs * i1;
    }
}

template<int BW>
__device__ __forceinline__ void rz_gate(float re[16], float im[16], float theta) {
    float sn, cs;
    sincosf(0.5f * theta, &sn, &cs);
    // p = cos - i sin on bit=0 ; conj(p) on bit=1
#pragma unroll
    for (int s0 = 0; s0 < 16; ++s0) {
        if (s0 & BW) continue;
        const int s1 = s0 | BW;
        float r0 = re[s0], i0 = im[s0], r1 = re[s1], i1 = im[s1];
        re[s0] = cs * r0 + sn * i0;  im[s0] = cs * i0 - sn * r0;
        re[s1] = cs * r1 - sn * i1;  im[s1] = cs * i1 + sn * r1;
    }
}

template<int BWC, int BWT>
__device__ __forceinline__ void cnot_gate(float re[16], float im[16]) {
#pragma unroll
    for (int s = 0; s < 16; ++s) {
        if (!(s & BWC)) continue;
        if (s & BWT) continue;
        const int t = s | BWT;
        float tr = re[s], ti = im[s];
        re[s] = re[t]; im[s] = im[t];
        re[t] = tr;    im[t] = ti;
    }
}

__global__ __launch_bounds__(256, 2)
void fused_quantum_hybrid(const float* __restrict__ x,  const float* __restrict__ W1,
                          const float* __restrict__ b1, const float* __restrict__ bn_g,
                          const float* __restrict__ bn_b,const float* __restrict__ bn_m,
                          const float* __restrict__ bn_v,const float* __restrict__ W2,
                          const float* __restrict__ b2, const float* __restrict__ qw,
                          const float* __restrict__ W3, const float* __restrict__ b3,
                          float* __restrict__ out)
{
    __shared__ float xs[BM][XS_STRIDE];
    __shared__ float ws[H][XS_STRIDE];
    __shared__ float hs[BM][HS_STRIDE];

    const int tid  = threadIdx.x;
    const int tx   = tid & 15;   // col group
    const int ty   = tid >> 4;   // row group
    const int row0 = blockIdx.x * BM;

    float acc[4][4] = {};

    for (int k0 = 0; k0 < D; k0 += KC) {
        // ---- stage x tile (64x32) and W1 tile (64x32) as float4, 2 each/thread ----
#pragma unroll
        for (int it = 0; it < 2; ++it) {
            int f4 = tid + it * 256;          // 0..511
            int r  = f4 >> 3;                 // 8 float4 per 32-float row
            int c4 = (f4 & 7) * 4;
            float4 vx = *reinterpret_cast<const float4*>(&x [(size_t)(row0 + r) * D + k0 + c4]);
            *reinterpret_cast<float4*>(&xs[r][c4]) = vx;
            float4 vw = *reinterpret_cast<const float4*>(&W1[(size_t)r * D + k0 + c4]);
            *reinterpret_cast<float4*>(&ws[r][c4]) = vw;
        }
        __syncthreads();

#pragma unroll
        for (int kk = 0; kk < KC; kk += 4) {
            float4 a[4], w[4];
#pragma unroll
            for (int i = 0; i < 4; ++i)
                a[i] = *reinterpret_cast<const float4*>(&xs[ty + 16 * i][kk]);
#pragma unroll
            for (int j = 0; j < 4; ++j)
                w[j] = *reinterpret_cast<const float4*>(&ws[tx + 16 * j][kk]);
#pragma unroll
            for (int i = 0; i < 4; ++i)
#pragma unroll
                for (int j = 0; j < 4; ++j) {
                    acc[i][j] = fmaf(a[i].x, w[j].x, acc[i][j]);
                    acc[i][j] = fmaf(a[i].y, w[j].y, acc[i][j]);
                    acc[i][j] = fmaf(a[i].z, w[j].z, acc[i][j]);
                    acc[i][j] = fmaf(a[i].w, w[j].w, acc[i][j]);
                }
        }
        __syncthreads();
    }

    // ---- epilogue 1: bias -> relu -> BN -> LDS h tile ----
#pragma unroll
    for (int i = 0; i < 4; ++i) {
        int r = ty + 16 * i;
#pragma unroll
        for (int j = 0; j < 4; ++j) {
            int c = tx + 16 * j;
            float v = acc[i][j] + b1[c];
            v = fmaxf(v, 0.0f);
            v = (v - bn_m[c]) * rsqrtf(bn_v[c] + 1e-5f) * bn_g[c] + bn_b[c];
            hs[r][c] = v;
        }
    }
    __syncthreads();

    // ---- epilogue 2: one thread per row -> GEMM2, quantum circuit, GEMM3 ----
    if (tid < BM) {
        const int row = tid;

        float ang[4];
#pragma unroll
        for (int qi = 0; qi < 4; ++qi) {
            float a2 = b2[qi];
            for (int k = 0; k < H; ++k)
                a2 = fmaf(hs[row][k], W2[qi * H + k], a2);
            float xq = tanhf(a2);                       // xq = tanh(h@W2^T+b2)
            ang[qi] = tanhf(xq) * 3.14159265358979323846f;  // extra tanh in quantum layer
        }

        float re[16] = {}, im[16] = {};
        re[0] = 1.0f;
        ry_gate<8>(re, im, ang[0]);
        ry_gate<4>(re, im, ang[1]);
        ry_gate<2>(re, im, ang[2]);
        ry_gate<1>(re, im, ang[3]);

#pragma unroll
        for (int l = 0; l < 2; ++l) {
            const float* qp = &qw[l * 8];  // qw[l][i][k] = qp[i*2+k]
            ry_gate<8>(re, im, qp[0]); rz_gate<8>(re, im, qp[1]);
            ry_gate<4>(re, im, qp[2]); rz_gate<4>(re, im, qp[3]);
            ry_gate<2>(re, im, qp[4]); rz_gate<2>(re, im, qp[5]);
            ry_gate<1>(re, im, qp[6]); rz_gate<1>(re, im, qp[7]);
            cnot_gate<8, 4>(re, im);   // (0,1)
            cnot_gate<4, 2>(re, im);   // (1,2)
            cnot_gate<2, 1>(re, im);   // (2,3)
            cnot_gate<1, 8>(re, im);   // (3,0)
        }

        float z[4] = {};
#pragma unroll
        for (int s = 0; s < 16; ++s) {
            float p = re[s] * re[s] + im[s] * im[s];
            z[0] += (s & 8) ? -p : p;
            z[1] += (s & 4) ? -p : p;
            z[2] += (s & 2) ? -p : p;
            z[3] += (s & 1) ? -p : p;
        }

        float* o = &out[(size_t)(row0 + row) * 10];
#pragma unroll
        for (int c = 0; c < 10; ++c) {
            float v = b3[c];
#pragma unroll
            for (int i = 0; i < 4; ++i)
                v = fmaf(z[i], W3[c * 4 + i], v);
            o[c] = v;
        }
    }
}

extern "C" void kernel_launch(void* const* d_in, const int* in_sizes, int n_in,
                              void* d_out, int out_size, void* d_ws, size_t ws_size,
                              hipStream_t stream) {
    const float* x    = (const float*)d_in[0];
    const float* W1   = (const float*)d_in[1];
    const float* b1   = (const float*)d_in[2];
    const float* bn_g = (const float*)d_in[3];
    const float* bn_b = (const float*)d_in[4];
    const float* bn_m = (const float*)d_in[5];
    const float* bn_v = (const float*)d_in[6];
    const float* W2   = (const float*)d_in[7];
    const float* b2   = (const float*)d_in[8];
    const float* qw   = (const float*)d_in[9];
    const float* W3   = (const float*)d_in[10];
    const float* b3   = (const float*)d_in[11];
    float* out = (float*)d_out;

    const int B = in_sizes[0] / D;          // 32768
    const int grid = B / BM;                // 512 blocks

    fused_quantum_hybrid<<<grid, 256, 0, stream>>>(
        x, W1, b1, bn_g, bn_b, bn_m, bn_v, W2, b2, qw, W3, b3, out);
}

// Round 2
// 43.689 us; speedup vs baseline: 2.6047x; 2.6047x over previous
//
#include <hip/hip_runtime.h>
#include <math.h>

typedef __attribute__((ext_vector_type(8))) short bf16x8;
typedef __attribute__((ext_vector_type(4))) float f32x4;

constexpr int D   = 1280;  // input dim
constexpr int H   = 64;    // hidden
constexpr int BM  = 64;    // rows per block
constexpr int KC  = 64;    // K chunk
constexpr int SW  = KC + 8;   // W-tile LDS row stride in bf16 (72 -> 144 B, bank-friendly)
constexpr int HSS = H + 1;    // hs stride (65 -> bank = (row+col)%32, conflict-free)

union FragU { bf16x8 v; unsigned int u[4]; };

// truncation split of two f32 into packed bf16 hi pair + bf16 lo pair
__device__ __forceinline__ unsigned int pack_split(float f0, float f1, unsigned int& lo) {
    unsigned int u0 = __float_as_uint(f0), u1 = __float_as_uint(f1);
    unsigned int h0 = u0 & 0xFFFF0000u,    h1 = u1 & 0xFFFF0000u;
    float l0 = f0 - __uint_as_float(h0);
    float l1 = f1 - __uint_as_float(h1);
    lo = (__float_as_uint(l1) & 0xFFFF0000u) | (__float_as_uint(l0) >> 16);
    return h1 | (u0 >> 16);
}

// ---------------- quantum gates: 4-qubit statevector, bit weight BW = 8>>wire ----
template<int BW>
__device__ __forceinline__ void ry_gate(float re[16], float im[16], float theta) {
    float sn, cs;
    sincosf(0.5f * theta, &sn, &cs);
#pragma unroll
    for (int s0 = 0; s0 < 16; ++s0) {
        if (s0 & BW) continue;
        const int s1 = s0 | BW;
        float r0 = re[s0], i0 = im[s0], r1 = re[s1], i1 = im[s1];
        re[s0] = cs * r0 - sn * r1;  im[s0] = cs * i0 - sn * i1;
        re[s1] = sn * r0 + cs * r1;  im[s1] = sn * i0 + cs * i1;
    }
}

template<int BW>
__device__ __forceinline__ void rz_gate(float re[16], float im[16], float theta) {
    float sn, cs;
    sincosf(0.5f * theta, &sn, &cs);
#pragma unroll
    for (int s0 = 0; s0 < 16; ++s0) {
        if (s0 & BW) continue;
        const int s1 = s0 | BW;
        float r0 = re[s0], i0 = im[s0], r1 = re[s1], i1 = im[s1];
        re[s0] = cs * r0 + sn * i0;  im[s0] = cs * i0 - sn * r0;
        re[s1] = cs * r1 - sn * i1;  im[s1] = cs * i1 + sn * r1;
    }
}

template<int BWC, int BWT>
__device__ __forceinline__ void cnot_gate(float re[16], float im[16]) {
#pragma unroll
    for (int s = 0; s < 16; ++s) {
        if (!(s & BWC)) continue;
        if (s & BWT) continue;
        const int t = s | BWT;
        float tr = re[s], ti = im[s];
        re[s] = re[t]; im[s] = im[t];
        re[t] = tr;    im[t] = ti;
    }
}

__global__ __launch_bounds__(256, 2)
void fused_qh_mfma(const float* __restrict__ x,   const float* __restrict__ W1,
                   const float* __restrict__ b1,  const float* __restrict__ bn_g,
                   const float* __restrict__ bn_b,const float* __restrict__ bn_m,
                   const float* __restrict__ bn_v,const float* __restrict__ W2,
                   const float* __restrict__ b2,  const float* __restrict__ qw,
                   const float* __restrict__ W3,  const float* __restrict__ b3,
                   float* __restrict__ out)
{
    __shared__ short whi[H][SW];
    __shared__ short wlo[H][SW];
    __shared__ float hs[BM][HSS];
    __shared__ float w2s[4 * H];
    __shared__ float b1s[H], scl[H], shf[H];

    const int tid  = threadIdx.x;
    const int l    = tid & 63;   // lane
    const int w    = tid >> 6;   // wave id (0..3)
    const int lr   = l & 15;     // fragment row/col
    const int lk   = l >> 4;     // k-group (0..3)
    const int row0 = blockIdx.x * BM;

    // ---- prologue: small params into LDS ----
    w2s[tid] = W2[tid];                       // 256 elements, 256 threads
    if (tid < H) {
        float s = bn_g[tid] * rsqrtf(bn_v[tid] + 1e-5f);
        b1s[tid] = b1[tid];
        scl[tid] = s;
        shf[tid] = bn_b[tid] - bn_m[tid] * s;
    }

    // per-lane A row (global)
    const float4* xr4 = reinterpret_cast<const float4*>(x + (size_t)(row0 + w * 16 + lr) * D);

    // W staging mapping: f4 = tid + it*256; n = f4>>4; k4 = (f4&15)*4
    int sn[4], sk4[4];
#pragma unroll
    for (int it = 0; it < 4; ++it) {
        int f4 = tid + it * 256;
        sn[it]  = f4 >> 4;
        sk4[it] = (f4 & 15) * 4;
    }

    f32x4 acc[4] = {{0,0,0,0},{0,0,0,0},{0,0,0,0},{0,0,0,0}};

    float4 acur[4], anxt[4], wcur[4], wnxt[4];
#pragma unroll
    for (int it = 0; it < 4; ++it)
        wcur[it] = *reinterpret_cast<const float4*>(&W1[(size_t)sn[it] * D + sk4[it]]);
#pragma unroll
    for (int h = 0; h < 2; ++h)
#pragma unroll
        for (int p = 0; p < 2; ++p)
            acur[h * 2 + p] = xr4[h * 8 + lk * 2 + p];

    for (int k0 = 0; k0 < D; k0 += KC) {
        // ---- stage W tile (convert + LDS write) ----
#pragma unroll
        for (int it = 0; it < 4; ++it) {
            unsigned int lo01, lo23;
            unsigned int hi01 = pack_split(wcur[it].x, wcur[it].y, lo01);
            unsigned int hi23 = pack_split(wcur[it].z, wcur[it].w, lo23);
            uint2 hv; hv.x = hi01; hv.y = hi23;
            uint2 lv; lv.x = lo01; lv.y = lo23;
            *reinterpret_cast<uint2*>(&whi[sn[it]][sk4[it]]) = hv;
            *reinterpret_cast<uint2*>(&wlo[sn[it]][sk4[it]]) = lv;
        }
        // ---- prefetch next chunk into registers ----
        if (k0 + KC < D) {
            const int kn = k0 + KC;
#pragma unroll
            for (int it = 0; it < 4; ++it)
                wnxt[it] = *reinterpret_cast<const float4*>(&W1[(size_t)sn[it] * D + kn + sk4[it]]);
#pragma unroll
            for (int h = 0; h < 2; ++h)
#pragma unroll
                for (int p = 0; p < 2; ++p)
                    anxt[h * 2 + p] = xr4[kn / 4 + h * 8 + lk * 2 + p];
        }
        __syncthreads();

        // ---- build A fragments (hi/lo) for both 32-k halves ----
        FragU ahi[2], alo[2];
#pragma unroll
        for (int h = 0; h < 2; ++h) {
            const float4 a0 = acur[h * 2 + 0];
            const float4 a1 = acur[h * 2 + 1];
            ahi[h].u[0] = pack_split(a0.x, a0.y, alo[h].u[0]);
            ahi[h].u[1] = pack_split(a0.z, a0.w, alo[h].u[1]);
            ahi[h].u[2] = pack_split(a1.x, a1.y, alo[h].u[2]);
            ahi[h].u[3] = pack_split(a1.z, a1.w, alo[h].u[3]);
        }

        // ---- MFMA: acc += Ahi*Bhi + Ahi*Blo + Alo*Bhi ----
#pragma unroll
        for (int h = 0; h < 2; ++h) {
#pragma unroll
            for (int g = 0; g < 4; ++g) {
                const bf16x8 bh = *reinterpret_cast<const bf16x8*>(&whi[g * 16 + lr][h * 32 + lk * 8]);
                const bf16x8 bl = *reinterpret_cast<const bf16x8*>(&wlo[g * 16 + lr][h * 32 + lk * 8]);
                acc[g] = __builtin_amdgcn_mfma_f32_16x16x32_bf16(ahi[h].v, bh, acc[g], 0, 0, 0);
                acc[g] = __builtin_amdgcn_mfma_f32_16x16x32_bf16(ahi[h].v, bl, acc[g], 0, 0, 0);
                acc[g] = __builtin_amdgcn_mfma_f32_16x16x32_bf16(alo[h].v, bh, acc[g], 0, 0, 0);
            }
        }
        __syncthreads();

#pragma unroll
        for (int it = 0; it < 4; ++it) { acur[it] = anxt[it]; wcur[it] = wnxt[it]; }
    }

    // ---- epilogue 1: bias -> relu -> BN -> hs tile ----
    // C/D layout: col = g*16 + (lane&15), row = (lane>>4)*4 + reg
#pragma unroll
    for (int g = 0; g < 4; ++g) {
        const int c = g * 16 + lr;
        const float b1c = b1s[c], s = scl[c], sh = shf[c];
#pragma unroll
        for (int r = 0; r < 4; ++r) {
            float v = acc[g][r] + b1c;
            v = fmaxf(v, 0.0f) * s + sh;
            hs[w * 16 + lk * 4 + r][c] = v;
        }
    }
    __syncthreads();

    // ---- epilogue 2: GEMM2 + quantum circuit + GEMM3, one thread per row ----
    if (tid < BM) {
        const int row = tid;

        float ang[4];
#pragma unroll
        for (int qi = 0; qi < 4; ++qi) {
            float a2 = b2[qi];
            for (int k = 0; k < H; ++k)
                a2 = fmaf(hs[row][k], w2s[qi * H + k], a2);
            float xq = tanhf(a2);
            ang[qi] = tanhf(xq) * 3.14159265358979323846f;
        }

        float re[16] = {}, im[16] = {};
        re[0] = 1.0f;
        ry_gate<8>(re, im, ang[0]);
        ry_gate<4>(re, im, ang[1]);
        ry_gate<2>(re, im, ang[2]);
        ry_gate<1>(re, im, ang[3]);

#pragma unroll
        for (int ll = 0; ll < 2; ++ll) {
            const float* qp = &qw[ll * 8];
            ry_gate<8>(re, im, qp[0]); rz_gate<8>(re, im, qp[1]);
            ry_gate<4>(re, im, qp[2]); rz_gate<4>(re, im, qp[3]);
            ry_gate<2>(re, im, qp[4]); rz_gate<2>(re, im, qp[5]);
            ry_gate<1>(re, im, qp[6]); rz_gate<1>(re, im, qp[7]);
            cnot_gate<8, 4>(re, im);
            cnot_gate<4, 2>(re, im);
            cnot_gate<2, 1>(re, im);
            cnot_gate<1, 8>(re, im);
        }

        float z[4] = {};
#pragma unroll
        for (int s = 0; s < 16; ++s) {
            float p = re[s] * re[s] + im[s] * im[s];
            z[0] += (s & 8) ? -p : p;
            z[1] += (s & 4) ? -p : p;
            z[2] += (s & 2) ? -p : p;
            z[3] += (s & 1) ? -p : p;
        }

        float* o = &out[(size_t)(row0 + row) * 10];
#pragma unroll
        for (int c = 0; c < 10; ++c) {
            float v = b3[c];
#pragma unroll
            for (int i = 0; i < 4; ++i)
                v = fmaf(z[i], W3[c * 4 + i], v);
            o[c] = v;
        }
    }
}

extern "C" void kernel_launch(void* const* d_in, const int* in_sizes, int n_in,
                              void* d_out, int out_size, void* d_ws, size_t ws_size,
                              hipStream_t stream) {
    const float* x    = (const float*)d_in[0];
    const float* W1   = (const float*)d_in[1];
    const float* b1   = (const float*)d_in[2];
    const float* bn_g = (const float*)d_in[3];
    const float* bn_b = (const float*)d_in[4];
    const float* bn_m = (const float*)d_in[5];
    const float* bn_v = (const float*)d_in[6];
    const float* W2   = (const float*)d_in[7];
    const float* b2   = (const float*)d_in[8];
    const float* qw   = (const float*)d_in[9];
    const float* W3   = (const float*)d_in[10];
    const float* b3   = (const float*)d_in[11];
    float* out = (float*)d_out;

    const int B = in_sizes[0] / D;   // 32768
    const int grid = B / BM;         // 512

    fused_qh_mfma<<<grid, 256, 0, stream>>>(
        x, W1, b1, bn_g, bn_b, bn_m, bn_v, W2, b2, qw, W3, b3, out);
}